// Round 2
// baseline (564.364 us; speedup 1.0000x reference)
//
#include <hip/hip_runtime.h>
#include <hip/hip_cooperative_groups.h>
#include <cstddef>

namespace cg = cooperative_groups;

#define NSTEP 10
#define DEG   16
#define TB    1024          // threads per block
// grid = E / TB = 64 blocks; E == N*DEG == 65536 for this problem

struct Params {
    const float *J, *bias, *gat_W, *gat_a;
    const float *W1, *b1, *W2, *b2, *W3, *b3;
    const int   *col, *rev, *ru, *cu, *u2e;
    int N, Eu;
    // outputs
    float *ro_out, *rp_out, *ent, *ci_out, *cij_out, *dom_out;
    // workspace
    float *f1g, *f2g, *cijW, *jsW;
    float *hidA, *hidB, *lnzA, *lnzB, *emA, *emB;
};

__global__ __launch_bounds__(TB) void k_fused(Params p) {
    cg::grid_group grid = cg::this_grid();

    __shared__ float sW2[64 * 64];        // 16 KB
    __shared__ float sh1[TB / 16][64];    // 16 KB (64 nodes/block)
    __shared__ float redA[TB / 64], redB[TB / 64];

    const int tidb = threadIdx.x;
    const int tid  = blockIdx.x * TB + tidb;
    const int i    = tid >> 4;       // node (thread group of 16)
    const int t    = tid & 15;       // in-edge slot within node
    const int g    = tid;            // out-edge index == 16*i + t (uniform degree)
    const int lane = tidb & 63;
    const int N    = p.N;

    // ================= S0: feat, GAT f1/f2, Ci MLP, em init =================
    for (int k = tidb; k < 64 * 64; k += TB) sW2[k] = p.W2[k];
    if (tid < 3) p.ent[tid] = 0.0f;

    const int j  = p.col[g];         // neighbor (edge g = i->j)
    const int rg = p.rev[g];         // reverse edge index of g
    const float Jv = p.J[(size_t)i * (size_t)N + (size_t)j];

    p.emA[2 * g] = 0.0f; p.emA[2 * g + 1] = 0.0f;   // em0 = log(1) = 0

    // row-sum of J over the 16 out-edges (butterfly within 16-group)
    float rs = Jv;
    rs += __shfl_xor(rs, 1); rs += __shfl_xor(rs, 2);
    rs += __shfl_xor(rs, 4); rs += __shfl_xor(rs, 8);

    const float b  = p.bias[i];
    const float f0 = -b, fb = b, fd = (float)DEG, fr = rs;

    // w1[k] = sum_h gat_W[k,h]*a1[h] ; w2[k] = ... a2[h]  (lanes 0..7 per wave)
    float s8 = 0.0f;
    if (lane < 8) {
        int k = lane & 3;
        const float* a = p.gat_a + ((lane < 4) ? 0 : 64);
        for (int h = 0; h < 64; ++h) s8 += p.gat_W[k * 64 + h] * a[h];
    }
    const float w10 = __shfl(s8, 0), w11 = __shfl(s8, 1), w12 = __shfl(s8, 2), w13 = __shfl(s8, 3);
    const float w20 = __shfl(s8, 4), w21 = __shfl(s8, 5), w22 = __shfl(s8, 6), w23 = __shfl(s8, 7);
    const float f1i = f0 * w10 + fb * w11 + fd * w12 + fr * w13;
    const float f2i = f0 * w20 + fb * w21 + fd * w22 + fr * w23;
    if (t == 0) { p.f1g[i] = f1i; p.f2g[i] = f2i; }

    // Ci MLP: 16 threads/node, 4 hidden units each
    const int nib = tidb >> 4;
    __syncthreads();                                  // sW2 loaded
    #pragma unroll
    for (int m = 0; m < 4; ++m) {
        int h = t + 16 * m;
        float a = f0 * p.W1[h] + fb * p.W1[64 + h] + fd * p.W1[128 + h]
                + fr * p.W1[192 + h] + p.b1[h];
        sh1[nib][h] = fmaxf(a, 0.0f);
    }
    __syncthreads();
    float civ = 0.0f;
    #pragma unroll
    for (int m = 0; m < 4; ++m) {
        int o = t + 16 * m;
        float acc = p.b2[o];
        for (int h = 0; h < 64; ++h) acc += sh1[nib][h] * sW2[h * 64 + o];
        civ += fmaxf(acc, 0.0f) * p.W3[o];
    }
    civ += __shfl_xor(civ, 1); civ += __shfl_xor(civ, 2);
    civ += __shfl_xor(civ, 4); civ += __shfl_xor(civ, 8);
    const float ci = civ + p.b3[0];
    if (t == 0) p.ci_out[i] = ci;

    __threadfence();
    grid.sync();

    // ================= S1: Cij, jscale, dom, initial node update ============
    const float f1j = p.f1g[j], f2j = p.f2g[j];
    float x1 = f1i + f2j; x1 = (x1 > 0.0f) ? x1 : 0.2f * x1;
    float x2 = f1j + f2i; x2 = (x2 > 0.0f) ? x2 : 0.2f * x2;
    const float C  = 0.5f * (expf(x1) + expf(x2));   // Cij symmetric: edge g and rev[g]
    const float js = Jv / C;                          // J symmetric too
    p.cijW[g] = C; p.jsW[g] = js;

    float sc = C;
    sc += __shfl_xor(sc, 1); sc += __shfl_xor(sc, 2);
    sc += __shfl_xor(sc, 4); sc += __shfl_xor(sc, 8);
    const float s  = ci + sc;
    const float cl = fmaxf(fabsf(s), 0.1f);
    const float d  = (s > 0.0f) ? cl : ((s < 0.0f) ? -cl : 0.0f);
    const float bs = b / d;
    if (t == 0) p.dom_out[i] = d;

    {   // initial node update (em = 0)
        float u0 = -bs, u1 = bs;
        float mm = fmaxf(u0, u1);
        float lz = mm + logf(expf(u0 - mm) + expf(u1 - mm));
        if (t == 0) {
            p.hidA[2 * i] = u0 - lz; p.hidA[2 * i + 1] = u1 - lz; p.lnzA[i] = lz;
        }
    }

    __threadfence();
    grid.sync();

    // ================= BP loop: 1 grid sync per step ========================
    float *hidP = p.hidA, *hidQ = p.hidB;
    float *lnzP = p.lnzA, *lnzQ = p.lnzB;
    float *emP  = p.emA,  *emQ  = p.emB;
    for (int step = 0; step < NSTEP; ++step) {
        // edge update for in-edge rev[g] = (j -> i); mu = em on edge g, stored at slot rev[g]
        float h0 = hidP[2 * j], h1 = hidP[2 * j + 1], lzj = lnzP[j];
        float mu0 = emP[2 * rg], mu1 = emP[2 * rg + 1];
        float a0 = h0 + lzj - mu0, a1 = h1 + lzj - mu1;
        float t0 = fmaxf( js + a0, -js + a1);
        float t1 = fmaxf(-js + a0,  js + a1);
        float m2 = fmaxf(t0, t1);
        float ls = m2 + logf(expf(t0 - m2) + expf(t1 - m2));
        float e0 = C * (t0 - ls), e1 = C * (t1 - ls);
        emQ[2 * g] = e0; emQ[2 * g + 1] = e1;

        // node update: sum in-edge messages over the 16-group
        float nm0 = e0, nm1 = e1;
        nm0 += __shfl_xor(nm0, 1); nm1 += __shfl_xor(nm1, 1);
        nm0 += __shfl_xor(nm0, 2); nm1 += __shfl_xor(nm1, 2);
        nm0 += __shfl_xor(nm0, 4); nm1 += __shfl_xor(nm1, 4);
        nm0 += __shfl_xor(nm0, 8); nm1 += __shfl_xor(nm1, 8);
        nm0 /= d; nm1 /= d;
        float v0 = -bs + nm0, v1 = bs + nm1;
        float mv = fmaxf(v0, v1);
        float lzn = mv + logf(expf(v0 - mv) + expf(v1 - mv));
        if (t == 0) {
            hidQ[2 * i] = v0 - lzn; hidQ[2 * i + 1] = v1 - lzn; lnzQ[i] = lzn;
        }
        __threadfence();
        grid.sync();
        float* tp;
        tp = hidP; hidP = hidQ; hidQ = tp;
        tp = lnzP; lnzP = lnzQ; lnzQ = tp;
        tp = emP;  emP  = emQ;  emQ  = tp;
    }
    // hidP/lnzP/emP now hold final values

    // ================= Epilogue: readouts + entropies =======================
    float nodeC = 0.0f, edgeC = 0.0f;
    if (tid < N) {
        float r0 = expf(hidP[2 * tid]), r1 = expf(hidP[2 * tid + 1]);
        p.ro_out[2 * tid] = r0; p.ro_out[2 * tid + 1] = r1;
        float H = -(r0 * logf(r0 + 1e-16f) + r1 * logf(r1 + 1e-16f));
        nodeC = p.ci_out[tid] * H;
    }
    if (tid < p.Eu) {
        int e  = p.u2e[tid], r = p.ru[tid], c = p.cu[tid];
        int er = p.rev[e];
        float jse = p.jsW[e];
        float Ce  = p.cijW[e];
        // em on edge e is at slot rev[e]=er; em on edge er is at slot e
        float ti0 = hidP[2 * c]     - emP[2 * er];
        float ti1 = hidP[2 * c + 1] - emP[2 * er + 1];
        float tj0 = hidP[2 * r]     - emP[2 * e];
        float tj1 = hidP[2 * r + 1] - emP[2 * e + 1];
        float L00 =  jse + ti0 + tj0;
        float L01 = -jse + ti1 + tj0;
        float L10 = -jse + ti0 + tj1;
        float L11 =  jse + ti1 + tj1;
        float mL = fmaxf(fmaxf(L00, L01), fmaxf(L10, L11));
        float p00 = expf(L00 - mL), p01 = expf(L01 - mL);
        float p10 = expf(L10 - mL), p11 = expf(L11 - mL);
        float inv = 1.0f / (p00 + p01 + p10 + p11);
        p00 *= inv; p01 *= inv; p10 *= inv; p11 *= inv;
        p.rp_out[4 * tid + 0] = p00; p.rp_out[4 * tid + 1] = p01;
        p.rp_out[4 * tid + 2] = p10; p.rp_out[4 * tid + 3] = p11;
        p.cij_out[tid] = Ce;
        float H = -(p00 * logf(p00 + 1e-16f) + p01 * logf(p01 + 1e-16f)
                  + p10 * logf(p10 + 1e-16f) + p11 * logf(p11 + 1e-16f));
        edgeC = Ce * H;
    }
    for (int off = 32; off > 0; off >>= 1) {
        nodeC += __shfl_down(nodeC, off);
        edgeC += __shfl_down(edgeC, off);
    }
    if (lane == 0) { redA[tidb >> 6] = nodeC; redB[tidb >> 6] = edgeC; }
    __syncthreads();
    if (tidb == 0) {
        float sn = 0.0f, se = 0.0f;
        for (int w = 0; w < TB / 64; ++w) { sn += redA[w]; se += redB[w]; }
        atomicAdd(&p.ent[0], sn + se);
        atomicAdd(&p.ent[1], sn);
        atomicAdd(&p.ent[2], se);
    }
}

extern "C" void kernel_launch(void* const* d_in, const int* in_sizes, int n_in,
                              void* d_out, int out_size, void* d_ws, size_t ws_size,
                              hipStream_t stream) {
    Params p;
    p.J     = (const float*)d_in[0];
    p.bias  = (const float*)d_in[1];
    p.gat_W = (const float*)d_in[2];
    p.gat_a = (const float*)d_in[3];
    p.W1    = (const float*)d_in[4];
    p.b1    = (const float*)d_in[5];
    p.W2    = (const float*)d_in[6];
    p.b2    = (const float*)d_in[7];
    p.W3    = (const float*)d_in[8];
    p.b3    = (const float*)d_in[9];
    p.col   = (const int*)d_in[11];
    p.rev   = (const int*)d_in[12];
    p.ru    = (const int*)d_in[13];
    p.cu    = (const int*)d_in[14];
    p.u2e   = (const int*)d_in[15];

    const int N  = in_sizes[1];
    const int E  = in_sizes[10];
    const int Eu = in_sizes[13];
    p.N = N; p.Eu = Eu;

    float* out = (float*)d_out;
    size_t OFF_RP  = 2 * (size_t)N;
    size_t OFF_ENT = OFF_RP + 4 * (size_t)Eu;
    p.ro_out  = out;
    p.rp_out  = out + OFF_RP;
    p.ent     = out + OFF_ENT;
    p.ci_out  = p.ent + 3;
    p.cij_out = p.ci_out + N;
    p.dom_out = p.cij_out + Eu;

    char* w = (char*)d_ws;
    auto carve = [&](size_t bytes) {
        void* q = (void*)w;
        w += (bytes + 255) & ~(size_t)255;
        return q;
    };
    p.f1g  = (float*)carve((size_t)N * 4);
    p.f2g  = (float*)carve((size_t)N * 4);
    p.cijW = (float*)carve((size_t)E * 4);
    p.jsW  = (float*)carve((size_t)E * 4);
    p.hidA = (float*)carve((size_t)N * 8);
    p.hidB = (float*)carve((size_t)N * 8);
    p.lnzA = (float*)carve((size_t)N * 4);
    p.lnzB = (float*)carve((size_t)N * 4);
    p.emA  = (float*)carve((size_t)E * 8);
    p.emB  = (float*)carve((size_t)E * 8);

    int nblk = E / TB;   // 64 blocks x 1024 threads == E threads
    void* args[] = { (void*)&p };
    hipLaunchCooperativeKernel((void*)k_fused, dim3(nblk), dim3(TB), args, 0, stream);
}

// Round 3
// 181.443 us; speedup vs baseline: 3.1104x; 3.1104x over previous
//
#include <hip/hip_runtime.h>
#include <cstddef>

#define TB    256
#define DEG   16
#define NSTEP 10
// This problem: N=4096, E=65536 (=N*DEG, uniform degree, row-sorted),
// Eu=32768. E and Eu are exact multiples of TB; grids launched exact.

// ---------------- K1: feat + GAT f1/f2 + Ci MLP + em0 + ent=0 ---------------
__global__ __launch_bounds__(TB) void k_setup1(
    const float* __restrict__ J, const float* __restrict__ bias,
    const float* __restrict__ gat_W, const float* __restrict__ gat_a,
    const float* __restrict__ W1, const float* __restrict__ b1,
    const float* __restrict__ W2, const float* __restrict__ b2,
    const float* __restrict__ W3, const float* __restrict__ b3,
    const int* __restrict__ col, int N,
    float* __restrict__ JvW, float* __restrict__ f1g, float* __restrict__ f2g,
    float* __restrict__ ci_out, float2* __restrict__ emA, float* __restrict__ ent)
{
    __shared__ float sW2[64 * 64];       // 16 KB
    __shared__ float sh1[TB / 16][65];   // +1 pad: 4 nibs/wave stride-65 -> no bank conflict
    const int tidb = threadIdx.x;
    const int g = blockIdx.x * TB + tidb;
    const int i = g >> 4, t = g & 15;
    const int lane = tidb & 63;

    for (int k = tidb; k < 64 * 64; k += TB) sW2[k] = W2[k];
    if (g < 3) ent[g] = 0.0f;

    const int j = col[g];
    const float Jv = J[(size_t)i * (size_t)N + (size_t)j];
    JvW[g] = Jv;
    emA[g] = make_float2(0.0f, 0.0f);    // em0 = log(1)

    float rs = Jv;                        // row-sum over the 16 out-edges
    rs += __shfl_xor(rs, 1); rs += __shfl_xor(rs, 2);
    rs += __shfl_xor(rs, 4); rs += __shfl_xor(rs, 8);

    const float b = bias[i];
    const float f0 = -b, fb = b, fd = (float)DEG, fr = rs;

    // w1[k] = sum_h gat_W[k,h]*a1[h], w2[k] = ... a2[h]  (lanes 0..7 of each wave)
    float s8 = 0.0f;
    if (lane < 8) {
        int k = lane & 3;
        const float* a = gat_a + ((lane < 4) ? 0 : 64);
        for (int h = 0; h < 64; ++h) s8 += gat_W[k * 64 + h] * a[h];
    }
    const float w10 = __shfl(s8, 0), w11 = __shfl(s8, 1), w12 = __shfl(s8, 2), w13 = __shfl(s8, 3);
    const float w20 = __shfl(s8, 4), w21 = __shfl(s8, 5), w22 = __shfl(s8, 6), w23 = __shfl(s8, 7);
    const float f1i = f0 * w10 + fb * w11 + fd * w12 + fr * w13;
    const float f2i = f0 * w20 + fb * w21 + fd * w22 + fr * w23;
    if (t == 0) { f1g[i] = f1i; f2g[i] = f2i; }

    // Ci MLP: 16 threads per node, 4 hidden units each
    const int nib = tidb >> 4;
    __syncthreads();
    #pragma unroll
    for (int m = 0; m < 4; ++m) {
        int h = t + 16 * m;
        float a = f0 * W1[h] + fb * W1[64 + h] + fd * W1[128 + h]
                + fr * W1[192 + h] + b1[h];
        sh1[nib][h] = fmaxf(a, 0.0f);
    }
    __syncthreads();
    float civ = 0.0f;
    #pragma unroll
    for (int m = 0; m < 4; ++m) {
        int o = t + 16 * m;
        float acc = b2[o];
        for (int h = 0; h < 64; ++h) acc += sh1[nib][h] * sW2[h * 64 + o];
        civ += fmaxf(acc, 0.0f) * W3[o];
    }
    civ += __shfl_xor(civ, 1); civ += __shfl_xor(civ, 2);
    civ += __shfl_xor(civ, 4); civ += __shfl_xor(civ, 8);
    if (t == 0) ci_out[i] = civ + b3[0];
}

// ---------------- K2: Cij, jscale, dom, bias_scale, hidden init -------------
__global__ __launch_bounds__(TB) void k_setup2(
    const float* __restrict__ bias, const int* __restrict__ col,
    const float* __restrict__ JvW, const float* __restrict__ f1g,
    const float* __restrict__ f2g, const float* __restrict__ ci_out,
    float* __restrict__ cijW, float* __restrict__ jsW,
    float* __restrict__ domW, float* __restrict__ bsW, float* __restrict__ dom_out,
    float2* __restrict__ hidA, float* __restrict__ lnzA)
{
    const int g = blockIdx.x * TB + threadIdx.x;
    const int i = g >> 4, t = g & 15;
    const int j = col[g];
    const float Jv = JvW[g];
    const float f1i = f1g[i], f2i = f2g[i], f1j = f1g[j], f2j = f2g[j];
    float x1 = f1i + f2j; x1 = (x1 > 0.0f) ? x1 : 0.2f * x1;
    float x2 = f1j + f2i; x2 = (x2 > 0.0f) ? x2 : 0.2f * x2;
    const float C = 0.5f * (expf(x1) + expf(x2));  // symmetric across g <-> rev[g]
    cijW[g] = C; jsW[g] = Jv / C;

    float sc = C;
    sc += __shfl_xor(sc, 1); sc += __shfl_xor(sc, 2);
    sc += __shfl_xor(sc, 4); sc += __shfl_xor(sc, 8);
    const float s = ci_out[i] + sc;
    const float cl = fmaxf(fabsf(s), 0.1f);
    const float d = (s > 0.0f) ? cl : ((s < 0.0f) ? -cl : 0.0f);
    const float bs = bias[i] / d;
    if (t == 0) {
        dom_out[i] = d; domW[i] = d; bsW[i] = bs;
        float u0 = -bs, u1 = bs;
        float mm = fmaxf(u0, u1);
        float lz = mm + logf(expf(u0 - mm) + expf(u1 - mm));
        hidA[i] = make_float2(u0 - lz, u1 - lz);
        lnzA[i] = lz;
    }
}

// ---------------- K3: fused BP step (edge msg + node update) ----------------
// Slot scheme: emX[g] (g = 16*i+t) holds the message on in-edge rev[g] = (j->i).
// `last` also fuses node readout + node entropy.
__global__ __launch_bounds__(TB) void k_step(
    const int* __restrict__ col, const int* __restrict__ rev,
    const float* __restrict__ jsW, const float* __restrict__ cijW,
    const float* __restrict__ domW, const float* __restrict__ bsW,
    const float2* __restrict__ hidP, const float* __restrict__ lnzP,
    const float2* __restrict__ emP,
    float2* __restrict__ hidQ, float* __restrict__ lnzQ, float2* __restrict__ emQ,
    int last, const float* __restrict__ ci_out,
    float2* __restrict__ ro_out, float* __restrict__ ent)
{
    __shared__ float red[TB / 64];
    const int g = blockIdx.x * TB + threadIdx.x;
    const int i = g >> 4, t = g & 15;
    const int j = col[g], rg = rev[g];
    const float js = jsW[g], C = cijW[g];

    const float2 hj = hidP[j];
    const float lzj = lnzP[j];
    const float2 mu = emP[rg];
    const float a0 = hj.x + lzj - mu.x, a1 = hj.y + lzj - mu.y;
    const float t0 = fmaxf( js + a0, -js + a1);
    const float t1 = fmaxf(-js + a0,  js + a1);
    const float m2 = fmaxf(t0, t1);
    const float ls = m2 + logf(expf(t0 - m2) + expf(t1 - m2));
    const float e0 = C * (t0 - ls), e1 = C * (t1 - ls);
    emQ[g] = make_float2(e0, e1);

    float nm0 = e0, nm1 = e1;            // node update over the 16 in-edges
    nm0 += __shfl_xor(nm0, 1); nm1 += __shfl_xor(nm1, 1);
    nm0 += __shfl_xor(nm0, 2); nm1 += __shfl_xor(nm1, 2);
    nm0 += __shfl_xor(nm0, 4); nm1 += __shfl_xor(nm1, 4);
    nm0 += __shfl_xor(nm0, 8); nm1 += __shfl_xor(nm1, 8);
    const float d = domW[i], bs = bsW[i];
    nm0 /= d; nm1 /= d;
    const float v0 = -bs + nm0, v1 = bs + nm1;
    const float mv = fmaxf(v0, v1);
    const float lzn = mv + logf(expf(v0 - mv) + expf(v1 - mv));
    const float h0 = v0 - lzn, h1 = v1 - lzn;
    if (t == 0) { hidQ[i] = make_float2(h0, h1); lnzQ[i] = lzn; }

    if (last) {
        float nodeC = 0.0f;
        if (t == 0) {
            float r0 = expf(h0), r1 = expf(h1);
            ro_out[i] = make_float2(r0, r1);
            float H = -(r0 * logf(r0 + 1e-16f) + r1 * logf(r1 + 1e-16f));
            nodeC = ci_out[i] * H;
        }
        for (int off = 32; off > 0; off >>= 1) nodeC += __shfl_down(nodeC, off);
        const int lane = threadIdx.x & 63, wv = threadIdx.x >> 6;
        if (lane == 0) red[wv] = nodeC;
        __syncthreads();
        if (threadIdx.x == 0) {
            float sn = red[0] + red[1] + red[2] + red[3];
            atomicAdd(&ent[0], sn);
            atomicAdd(&ent[1], sn);
        }
    }
}

// ---------------- K4: pairwise readout + edge entropy -----------------------
__global__ __launch_bounds__(TB) void k_epi(
    const int* __restrict__ ru, const int* __restrict__ cu,
    const int* __restrict__ u2e, const int* __restrict__ rev,
    const float* __restrict__ jsW, const float* __restrict__ cijW,
    const float2* __restrict__ hidF, const float2* __restrict__ emF,
    float4* __restrict__ rp_out, float* __restrict__ cij_out,
    float* __restrict__ ent)
{
    __shared__ float red[TB / 64];
    const int u = blockIdx.x * TB + threadIdx.x;
    const int e = u2e[u], r = ru[u], c = cu[u];
    const int er = rev[e];
    const float jse = jsW[e];
    const float Ce  = cijW[e];
    const float2 hc = hidF[c], hr = hidF[r];
    const float2 eme = emF[er];   // message on edge e lives at slot rev[e]
    const float2 emr = emF[e];    // message on edge rev[e] lives at slot e
    const float ti0 = hc.x - eme.x, ti1 = hc.y - eme.y;
    const float tj0 = hr.x - emr.x, tj1 = hr.y - emr.y;
    const float L00 =  jse + ti0 + tj0;
    const float L01 = -jse + ti1 + tj0;
    const float L10 = -jse + ti0 + tj1;
    const float L11 =  jse + ti1 + tj1;
    const float mL = fmaxf(fmaxf(L00, L01), fmaxf(L10, L11));
    float p00 = expf(L00 - mL), p01 = expf(L01 - mL);
    float p10 = expf(L10 - mL), p11 = expf(L11 - mL);
    const float inv = 1.0f / (p00 + p01 + p10 + p11);
    p00 *= inv; p01 *= inv; p10 *= inv; p11 *= inv;
    rp_out[u] = make_float4(p00, p01, p10, p11);
    cij_out[u] = Ce;
    const float H = -(p00 * logf(p00 + 1e-16f) + p01 * logf(p01 + 1e-16f)
                    + p10 * logf(p10 + 1e-16f) + p11 * logf(p11 + 1e-16f));
    float edgeC = Ce * H;
    for (int off = 32; off > 0; off >>= 1) edgeC += __shfl_down(edgeC, off);
    const int lane = threadIdx.x & 63, wv = threadIdx.x >> 6;
    if (lane == 0) red[wv] = edgeC;
    __syncthreads();
    if (threadIdx.x == 0) {
        float se = red[0] + red[1] + red[2] + red[3];
        atomicAdd(&ent[0], se);
        atomicAdd(&ent[2], se);
    }
}

extern "C" void kernel_launch(void* const* d_in, const int* in_sizes, int n_in,
                              void* d_out, int out_size, void* d_ws, size_t ws_size,
                              hipStream_t stream) {
    const float* J     = (const float*)d_in[0];
    const float* bias  = (const float*)d_in[1];
    const float* gat_W = (const float*)d_in[2];
    const float* gat_a = (const float*)d_in[3];
    const float* W1    = (const float*)d_in[4];
    const float* b1    = (const float*)d_in[5];
    const float* W2    = (const float*)d_in[6];
    const float* b2    = (const float*)d_in[7];
    const float* W3    = (const float*)d_in[8];
    const float* b3    = (const float*)d_in[9];
    const int*   col   = (const int*)d_in[11];
    const int*   rev   = (const int*)d_in[12];
    const int*   ru    = (const int*)d_in[13];
    const int*   cu    = (const int*)d_in[14];
    const int*   u2e   = (const int*)d_in[15];

    const int N  = in_sizes[1];
    const int E  = in_sizes[10];
    const int Eu = in_sizes[13];

    float* out = (float*)d_out;
    size_t OFF_RP  = 2 * (size_t)N;
    size_t OFF_ENT = OFF_RP + 4 * (size_t)Eu;
    float2* ro_out  = (float2*)out;
    float4* rp_out  = (float4*)(out + OFF_RP);
    float*  ent     = out + OFF_ENT;
    float*  ci_out  = ent + 3;
    float*  cij_out = ci_out + N;
    float*  dom_out = cij_out + Eu;

    char* w = (char*)d_ws;
    auto carve = [&](size_t bytes) {
        void* q = (void*)w;
        w += (bytes + 255) & ~(size_t)255;
        return q;
    };
    float*  JvW  = (float*)carve((size_t)E * 4);
    float*  cijW = (float*)carve((size_t)E * 4);
    float*  jsW  = (float*)carve((size_t)E * 4);
    float*  f1g  = (float*)carve((size_t)N * 4);
    float*  f2g  = (float*)carve((size_t)N * 4);
    float*  domW = (float*)carve((size_t)N * 4);
    float*  bsW  = (float*)carve((size_t)N * 4);
    float2* hidA = (float2*)carve((size_t)N * 8);
    float2* hidB = (float2*)carve((size_t)N * 8);
    float*  lnzA = (float*)carve((size_t)N * 4);
    float*  lnzB = (float*)carve((size_t)N * 4);
    float2* emA  = (float2*)carve((size_t)E * 8);
    float2* emB  = (float2*)carve((size_t)E * 8);

    const int gE  = E / TB;    // 256
    const int gEu = Eu / TB;   // 128

    k_setup1<<<gE, TB, 0, stream>>>(J, bias, gat_W, gat_a, W1, b1, W2, b2, W3, b3,
                                    col, N, JvW, f1g, f2g, ci_out, emA, ent);
    k_setup2<<<gE, TB, 0, stream>>>(bias, col, JvW, f1g, f2g, ci_out,
                                    cijW, jsW, domW, bsW, dom_out, hidA, lnzA);

    float2 *hidP = hidA, *hidQ = hidB, *emP = emA, *emQ = emB;
    float  *lnzP = lnzA, *lnzQ = lnzB;
    for (int s = 0; s < NSTEP; ++s) {
        int last = (s == NSTEP - 1) ? 1 : 0;
        k_step<<<gE, TB, 0, stream>>>(col, rev, jsW, cijW, domW, bsW,
                                      hidP, lnzP, emP, hidQ, lnzQ, emQ,
                                      last, ci_out, ro_out, ent);
        float2* t2;
        t2 = hidP; hidP = hidQ; hidQ = t2;
        t2 = emP;  emP  = emQ;  emQ  = t2;
        float* t1;
        t1 = lnzP; lnzP = lnzQ; lnzQ = t1;
    }
    // hidP/emP now hold final values
    k_epi<<<gEu, TB, 0, stream>>>(ru, cu, u2e, rev, jsW, cijW, hidP, emP,
                                  rp_out, cij_out, ent);
}

// Round 4
// 177.169 us; speedup vs baseline: 3.1855x; 1.0241x over previous
//
#include <hip/hip_runtime.h>
#include <cstddef>

#define TB    256
#define DEG   16
#define NSTEP 10
// Problem constants: N=4096, E=65536 (=N*DEG, uniform degree, row-major sorted
// so out-edges of node i are exactly [16i,16i+16)), Eu=32768.
// Slot scheme: em buffer slot g (g=16i+t) holds the message on edge rev[g]=(j->i),
// so node i's incoming messages are slots [16i,16i+16) -> 16-lane shuffle reduce.
// We propagate u = hidden + lnZ (the only combination the BP recurrence needs);
// hidden is recovered as u - lse(u) only at readout.

// ---------------- K1: fused setup -------------------------------------------
// feat + GAT f1/f2 (own + redundant neighbor) + Cij/jscale + Ci MLP + dom/bs +
// u init + ent zero. One kernel, no cross-block deps (neighbor f recomputed).
__global__ __launch_bounds__(TB) void k_setup(
    const float* __restrict__ J, const float* __restrict__ bias,
    const float* __restrict__ gat_W, const float* __restrict__ gat_a,
    const float* __restrict__ W1, const float* __restrict__ b1,
    const float* __restrict__ W2, const float* __restrict__ b2,
    const float* __restrict__ W3, const float* __restrict__ b3,
    const int* __restrict__ col, const int* __restrict__ rev, int N,
    int4* __restrict__ edgeP, float2* __restrict__ dbW, float2* __restrict__ uA,
    float* __restrict__ ci_out, float* __restrict__ dom_out, float* __restrict__ ent)
{
    __shared__ float sW2[64 * 64];       // 16 KB
    __shared__ float sh1[TB / 16][65];   // +1 pad: no bank conflicts
    const int tidb = threadIdx.x;
    const int g = blockIdx.x * TB + tidb;
    const int i = g >> 4, t = g & 15;
    const int lane = tidb & 63;

    for (int k = tidb; k < 64 * 64; k += TB) sW2[k] = W2[k];
    if (g < 3) ent[g] = 0.0f;

    const int j = col[g];
    const float Jv = J[(size_t)i * (size_t)N + (size_t)j];

    // rs_i: butterfly over the group's 16 out-edge J values
    float rs = Jv;
    rs += __shfl_xor(rs, 1); rs += __shfl_xor(rs, 2);
    rs += __shfl_xor(rs, 4); rs += __shfl_xor(rs, 8);

    // rs_j: redundant sequential row-sum for the neighbor (L2-hit loads)
    float rsj = 0.0f;
    {
        const int* colj = col + 16 * j;
        const float* Jrow = J + (size_t)j * (size_t)N;
        #pragma unroll 4
        for (int tt = 0; tt < 16; ++tt) rsj += Jrow[colj[tt]];
    }

    const float bi = bias[i], bj = bias[j];

    // w1[k] = sum_h gat_W[k,h]*a1[h], w2[k] = ... a2[h]  (lanes 0..7 per wave)
    float s8 = 0.0f;
    if (lane < 8) {
        int k = lane & 3;
        const float* a = gat_a + ((lane < 4) ? 0 : 64);
        for (int h = 0; h < 64; ++h) s8 += gat_W[k * 64 + h] * a[h];
    }
    const float w10 = __shfl(s8, 0), w11 = __shfl(s8, 1), w12 = __shfl(s8, 2), w13 = __shfl(s8, 3);
    const float w20 = __shfl(s8, 4), w21 = __shfl(s8, 5), w22 = __shfl(s8, 6), w23 = __shfl(s8, 7);
    const float fd = (float)DEG;
    const float f1i = -bi * w10 + bi * w11 + fd * w12 + rs  * w13;
    const float f2i = -bi * w20 + bi * w21 + fd * w22 + rs  * w23;
    const float f1j = -bj * w10 + bj * w11 + fd * w12 + rsj * w13;
    const float f2j = -bj * w20 + bj * w21 + fd * w22 + rsj * w23;

    float x1 = f1i + f2j; x1 = (x1 > 0.0f) ? x1 : 0.2f * x1;
    float x2 = f1j + f2i; x2 = (x2 > 0.0f) ? x2 : 0.2f * x2;
    const float C  = 0.5f * (expf(x1) + expf(x2));  // symmetric across g <-> rev[g]
    const float js = Jv / C;
    edgeP[g] = make_int4(j, rev[g], __float_as_int(js), __float_as_int(C));

    float sc = C;
    sc += __shfl_xor(sc, 1); sc += __shfl_xor(sc, 2);
    sc += __shfl_xor(sc, 4); sc += __shfl_xor(sc, 8);

    // Ci MLP: 16 threads per node, 4 hidden units each
    const int nib = tidb >> 4;
    __syncthreads();
    #pragma unroll
    for (int m = 0; m < 4; ++m) {
        int h = t + 16 * m;
        float a = -bi * W1[h] + bi * W1[64 + h] + fd * W1[128 + h]
                + rs * W1[192 + h] + b1[h];
        sh1[nib][h] = fmaxf(a, 0.0f);
    }
    __syncthreads();
    float civ = 0.0f;
    #pragma unroll
    for (int m = 0; m < 4; ++m) {
        int o = t + 16 * m;
        float acc = b2[o];
        for (int h = 0; h < 64; ++h) acc += sh1[nib][h] * sW2[h * 64 + o];
        civ += fmaxf(acc, 0.0f) * W3[o];
    }
    civ += __shfl_xor(civ, 1); civ += __shfl_xor(civ, 2);
    civ += __shfl_xor(civ, 4); civ += __shfl_xor(civ, 8);
    const float ci = civ + b3[0];

    const float s  = ci + sc;
    const float cl = fmaxf(fabsf(s), 0.1f);
    const float d  = (s > 0.0f) ? cl : ((s < 0.0f) ? -cl : 0.0f);
    const float bs = bi / d;
    if (t == 0) {
        ci_out[i] = ci; dom_out[i] = d;
        dbW[i] = make_float2(d, bs);
        uA[i]  = make_float2(-bs, bs);   // u0 = bx_scale (em0 = 0)
    }
}

// ---------------- K2: fused BP step (edge msg + node update on u) -----------
__global__ __launch_bounds__(TB) void k_step(
    const int4* __restrict__ edgeP, const float2* __restrict__ dbW,
    const float2* __restrict__ uP, const float2* __restrict__ emP,
    float2* __restrict__ uQ, float2* __restrict__ emQ,
    int first, int last, const float* __restrict__ ci_out,
    float2* __restrict__ ro_out, float* __restrict__ ent)
{
    __shared__ float red[TB / 64];
    const int g = blockIdx.x * TB + threadIdx.x;
    const int i = g >> 4, t = g & 15;
    const int4 ep = edgeP[g];
    const int j = ep.x, rg = ep.y;
    const float js = __int_as_float(ep.z), C = __int_as_float(ep.w);

    const float2 uj = uP[j];             // = hidden[j] + lnZ[j]
    float mu0 = 0.0f, mu1 = 0.0f;
    if (!first) { const float2 mu = emP[rg]; mu0 = mu.x; mu1 = mu.y; }
    const float a0 = uj.x - mu0, a1 = uj.y - mu1;
    const float t0 = fmaxf( js + a0, -js + a1);
    const float t1 = fmaxf(-js + a0,  js + a1);
    const float m2 = fmaxf(t0, t1);
    const float ls = m2 + logf(expf(t0 - m2) + expf(t1 - m2));
    const float e0 = C * (t0 - ls), e1 = C * (t1 - ls);
    emQ[g] = make_float2(e0, e1);

    float nm0 = e0, nm1 = e1;            // sum the node's 16 incoming messages
    nm0 += __shfl_xor(nm0, 1); nm1 += __shfl_xor(nm1, 1);
    nm0 += __shfl_xor(nm0, 2); nm1 += __shfl_xor(nm1, 2);
    nm0 += __shfl_xor(nm0, 4); nm1 += __shfl_xor(nm1, 4);
    nm0 += __shfl_xor(nm0, 8); nm1 += __shfl_xor(nm1, 8);
    const float2 db = dbW[i];
    const float v0 = -db.y + nm0 / db.x, v1 = db.y + nm1 / db.x;
    if (t == 0) uQ[i] = make_float2(v0, v1);   // u_new = v (no lse needed)

    if (last) {
        float nodeC = 0.0f;
        if (t == 0) {
            const float mv = fmaxf(v0, v1);
            const float lz = mv + logf(expf(v0 - mv) + expf(v1 - mv));
            const float r0 = expf(v0 - lz), r1 = expf(v1 - lz);
            ro_out[i] = make_float2(r0, r1);
            const float H = -(r0 * logf(r0 + 1e-16f) + r1 * logf(r1 + 1e-16f));
            nodeC = ci_out[i] * H;
        }
        for (int off = 32; off > 0; off >>= 1) nodeC += __shfl_down(nodeC, off);
        const int lane = threadIdx.x & 63, wv = threadIdx.x >> 6;
        if (lane == 0) red[wv] = nodeC;
        __syncthreads();
        if (threadIdx.x == 0) {
            const float sn = red[0] + red[1] + red[2] + red[3];
            atomicAdd(&ent[0], sn);
            atomicAdd(&ent[1], sn);
        }
    }
}

// ---------------- K3: pairwise readout + edge entropy -----------------------
__global__ __launch_bounds__(TB) void k_epi(
    const int* __restrict__ ru, const int* __restrict__ cu,
    const int* __restrict__ u2e, const int4* __restrict__ edgeP,
    const float2* __restrict__ uF, const float2* __restrict__ emF,
    float4* __restrict__ rp_out, float* __restrict__ cij_out,
    float* __restrict__ ent)
{
    __shared__ float red[TB / 64];
    const int u = blockIdx.x * TB + threadIdx.x;
    const int e = u2e[u], r = ru[u], c = cu[u];
    const int4 ep = edgeP[e];
    const int er = ep.y;
    const float jse = __int_as_float(ep.z), Ce = __int_as_float(ep.w);

    const float2 uc = uF[c], ur = uF[r];
    const float mc  = fmaxf(uc.x, uc.y);
    const float lc  = mc + logf(expf(uc.x - mc) + expf(uc.y - mc));
    const float mr  = fmaxf(ur.x, ur.y);
    const float lr  = mr + logf(expf(ur.x - mr) + expf(ur.y - mr));
    const float2 eme = emF[er];   // message on edge e lives at slot rev[e]
    const float2 emr = emF[e];    // message on edge rev[e] lives at slot e
    const float ti0 = (uc.x - lc) - eme.x, ti1 = (uc.y - lc) - eme.y;
    const float tj0 = (ur.x - lr) - emr.x, tj1 = (ur.y - lr) - emr.y;
    const float L00 =  jse + ti0 + tj0;
    const float L01 = -jse + ti1 + tj0;
    const float L10 = -jse + ti0 + tj1;
    const float L11 =  jse + ti1 + tj1;
    const float mL = fmaxf(fmaxf(L00, L01), fmaxf(L10, L11));
    float p00 = expf(L00 - mL), p01 = expf(L01 - mL);
    float p10 = expf(L10 - mL), p11 = expf(L11 - mL);
    const float inv = 1.0f / (p00 + p01 + p10 + p11);
    p00 *= inv; p01 *= inv; p10 *= inv; p11 *= inv;
    rp_out[u] = make_float4(p00, p01, p10, p11);
    cij_out[u] = Ce;
    const float H = -(p00 * logf(p00 + 1e-16f) + p01 * logf(p01 + 1e-16f)
                    + p10 * logf(p10 + 1e-16f) + p11 * logf(p11 + 1e-16f));
    float edgeC = Ce * H;
    for (int off = 32; off > 0; off >>= 1) edgeC += __shfl_down(edgeC, off);
    const int lane = threadIdx.x & 63, wv = threadIdx.x >> 6;
    if (lane == 0) red[wv] = edgeC;
    __syncthreads();
    if (threadIdx.x == 0) {
        const float se = red[0] + red[1] + red[2] + red[3];
        atomicAdd(&ent[0], se);
        atomicAdd(&ent[2], se);
    }
}

extern "C" void kernel_launch(void* const* d_in, const int* in_sizes, int n_in,
                              void* d_out, int out_size, void* d_ws, size_t ws_size,
                              hipStream_t stream) {
    const float* J     = (const float*)d_in[0];
    const float* bias  = (const float*)d_in[1];
    const float* gat_W = (const float*)d_in[2];
    const float* gat_a = (const float*)d_in[3];
    const float* W1    = (const float*)d_in[4];
    const float* b1    = (const float*)d_in[5];
    const float* W2    = (const float*)d_in[6];
    const float* b2    = (const float*)d_in[7];
    const float* W3    = (const float*)d_in[8];
    const float* b3    = (const float*)d_in[9];
    const int*   col   = (const int*)d_in[11];
    const int*   rev   = (const int*)d_in[12];
    const int*   ru    = (const int*)d_in[13];
    const int*   cu    = (const int*)d_in[14];
    const int*   u2e   = (const int*)d_in[15];

    const int N  = in_sizes[1];
    const int E  = in_sizes[10];
    const int Eu = in_sizes[13];

    float* out = (float*)d_out;
    size_t OFF_RP  = 2 * (size_t)N;
    size_t OFF_ENT = OFF_RP + 4 * (size_t)Eu;
    float2* ro_out  = (float2*)out;
    float4* rp_out  = (float4*)(out + OFF_RP);
    float*  ent     = out + OFF_ENT;
    float*  ci_out  = ent + 3;
    float*  cij_out = ci_out + N;
    float*  dom_out = cij_out + Eu;

    char* w = (char*)d_ws;
    auto carve = [&](size_t bytes) {
        void* q = (void*)w;
        w += (bytes + 255) & ~(size_t)255;
        return q;
    };
    int4*   edgeP = (int4*)carve((size_t)E * 16);
    float2* dbW   = (float2*)carve((size_t)N * 8);
    float2* uA    = (float2*)carve((size_t)N * 8);
    float2* uB    = (float2*)carve((size_t)N * 8);
    float2* emA   = (float2*)carve((size_t)E * 8);
    float2* emB   = (float2*)carve((size_t)E * 8);

    const int gE  = E / TB;    // 256
    const int gEu = Eu / TB;   // 128

    k_setup<<<gE, TB, 0, stream>>>(J, bias, gat_W, gat_a, W1, b1, W2, b2, W3, b3,
                                   col, rev, N, edgeP, dbW, uA,
                                   ci_out, dom_out, ent);

    float2 *uP = uA, *uQ = uB, *emP = emA, *emQ = emB;
    for (int s = 0; s < NSTEP; ++s) {
        const int first = (s == 0) ? 1 : 0;
        const int last  = (s == NSTEP - 1) ? 1 : 0;
        k_step<<<gE, TB, 0, stream>>>(edgeP, dbW, uP, emP, uQ, emQ,
                                      first, last, ci_out, ro_out, ent);
        float2* tp;
        tp = uP;  uP  = uQ;  uQ  = tp;
        tp = emP; emP = emQ; emQ = tp;
    }
    // uP/emP hold final values
    k_epi<<<gEu, TB, 0, stream>>>(ru, cu, u2e, edgeP, uP, emP,
                                  rp_out, cij_out, ent);
}